// Round 2
// baseline (630.162 us; speedup 1.0000x reference)
//
#include <hip/hip_runtime.h>
#include <hip/hip_bf16.h>
#include <math.h>

// dims
#define Bb 2
#define Nn 2048
#define Cc 256
#define Kk 64
#define Hh 4
#define DHh 32
#define DMm 128
#define DIi 16
#define Ll 3
#define Ss 64
#define OUTn 10

__device__ __forceinline__ float gelu_exact(float x) {
    return 0.5f * x * (1.0f + erff(x * 0.70710678118654752f));
}

__device__ __forceinline__ float dot128(const float* a, const float* __restrict__ w) {
    float s = 0.f;
#pragma unroll 16
    for (int e = 0; e < 128; ++e) s = fmaf(a[e], w[e], s);
    return s;
}

template<int NT>
__device__ __forceinline__ float blk_sum(float v, float* red, int t) {
    red[t] = v; __syncthreads();
#pragma unroll
    for (int s = NT >> 1; s > 0; s >>= 1) {
        if (t < s) red[t] += red[t + s];
        __syncthreads();
    }
    float r = red[0];
    __syncthreads();
    return r;
}

template<int NT>
__device__ __forceinline__ float blk_max(float v, float* red, int t) {
    red[t] = v; __syncthreads();
#pragma unroll
    for (int s = NT >> 1; s > 0; s >>= 1) {
        if (t < s) red[t] = fmaxf(red[t], red[t + s]);
        __syncthreads();
    }
    float r = red[0];
    __syncthreads();
    return r;
}

// ---------------- K1: top-k (full bitonic sort of 2048, descending, tie -> lower idx) --------
__global__ __launch_bounds__(1024) void k_topk(const float* __restrict__ x,
                                               float* __restrict__ vals,
                                               float* __restrict__ mz) {
    __shared__ float key[Nn];
    __shared__ int   idx[Nn];
    const int b = blockIdx.x, t = threadIdx.x;
    for (int i = t; i < Nn; i += 1024) { key[i] = x[b * Nn + i]; idx[i] = i; }
    __syncthreads();
    for (int k = 2; k <= Nn; k <<= 1) {
        for (int j = k >> 1; j > 0; j >>= 1) {
            for (int i = t; i < Nn; i += 1024) {
                int ixj = i ^ j;
                if (ixj > i) {
                    float va = key[i], vb = key[ixj];
                    int ia = idx[i], ib = idx[ixj];
                    // strict "a greater" in descending-with-idx-tiebreak order
                    bool aG = (va > vb) || (va == vb && ia < ib);
                    bool desc = ((i & k) == 0);
                    bool dosw = desc ? (!aG) : aG;
                    if (dosw) { key[i] = vb; key[ixj] = va; idx[i] = ib; idx[ixj] = ia; }
                }
            }
            __syncthreads();
        }
    }
    if (t < Cc) {
        vals[b * Cc + t] = log1pf(fmaxf(key[t], 0.f));
        mz[b * Cc + t] = (float)idx[t];
    }
}

// ---------------- K2: binding encoder ----------------
__global__ __launch_bounds__(128) void k_encode(const float* __restrict__ vals,
                                                const float* __restrict__ mz,
                                                const float* __restrict__ emb_roles,
                                                const float* __restrict__ filler_w,
                                                const float* __restrict__ conv_w,
                                                const float* __restrict__ conv_b,
                                                const float* __restrict__ outer_w,
                                                const float* __restrict__ g,
                                                const float* __restrict__ bb,
                                                float* __restrict__ bnd) {
    __shared__ float roles[DIi], fill[DIi], outerv[DIi * DIi], red[128];
    const int bc = blockIdx.x;
    const int b = bc >> 8, c = bc & 255;
    const int t = threadIdx.x;
    const float NEG = -1.3157629102823120f; // -ln(10000)/7
    if (t < DIi) {
        float mzv = mz[bc];
        float rr;
        if (t < 8) rr = sinf(mzv * expf((float)t * NEG));
        else       rr = cosf(mzv * expf((float)(t - 8) * NEG));
        roles[t] = rr + emb_roles[c * DIi + t];
    } else if (t < 2 * DIi) {
        int e = t - DIi;
        float vc = vals[bc];
        float fp = vc * filler_w[e];
        float acc = conv_b[e];
#pragma unroll
        for (int kk = 0; kk < 5; ++kk) {
            int pos = c - 2 + kk;
            pos = pos < 0 ? -pos : (pos >= Cc ? 2 * Cc - 2 - pos : pos);
            acc = fmaf(vals[b * Cc + pos], conv_w[e * 5 + kk], acc);
        }
        fill[e] = gelu_exact(fp + gelu_exact(acc));
    }
    __syncthreads();
    outerv[t]       = roles[t >> 4] * fill[t & 15];
    outerv[t + 128] = roles[(t + 128) >> 4] * fill[t & 15];
    __syncthreads();
    float acc = 0.f;
    const float* wrow = outer_w + t * 256;
#pragma unroll 16
    for (int e = 0; e < 256; ++e) acc = fmaf(outerv[e], wrow[e], acc);
    float mean = blk_sum<128>(acc, red, t) * (1.f / 128.f);
    float d0 = acc - mean;
    float var = blk_sum<128>(d0 * d0, red, t) * (1.f / 128.f);
    bnd[bc * DMm + t] = d0 / sqrtf(var + 1e-5f) * g[t] + bb[t];
}

// ---------------- K3: QKV + qp/kp projections (per layer) ----------------
__global__ __launch_bounds__(128) void k_qkv(const float* __restrict__ bnd,
                                             const float* __restrict__ qw, const float* __restrict__ qb,
                                             const float* __restrict__ kw, const float* __restrict__ kb,
                                             const float* __restrict__ vw, const float* __restrict__ vb,
                                             const float* __restrict__ w1,
                                             float* __restrict__ q, float* __restrict__ k,
                                             float* __restrict__ v, float* __restrict__ qp,
                                             float* __restrict__ kp) {
    __shared__ float brow[DMm], qr[DMm], kr[DMm];
    const int bc = blockIdx.x, t = threadIdx.x;
    const int b = bc >> 8, c = bc & 255;
    brow[t] = bnd[bc * DMm + t];
    __syncthreads();
    float qv = qb[t] + dot128(brow, qw + t * DMm);
    float kv = kb[t] + dot128(brow, kw + t * DMm);
    float vv = vb[t] + dot128(brow, vw + t * DMm);
    const int h = t >> 5, d = t & 31;
    const int gi = ((b * Hh + h) * Cc + c) * DHh + d;
    q[gi] = qv; k[gi] = kv; v[gi] = vv;
    qr[t] = qv; kr[t] = kv;
    __syncthreads();
    float accq = 0.f, acck = 0.f;
    const float* wr = w1 + d * 96;
#pragma unroll
    for (int e = 0; e < DHh; ++e) {
        accq = fmaf(qr[h * 32 + e], wr[e], accq);
        acck = fmaf(kr[h * 32 + e], wr[32 + e], acck);
    }
    qp[gi] = accq; kp[gi] = acck;
}

// ---------------- K4: scores + top-K mask + softmax + AV (per layer, hot kernel) -------------
__global__ __launch_bounds__(256) void k_attn(const float* __restrict__ q,
                                              const float* __restrict__ k,
                                              const float* __restrict__ v,
                                              const float* __restrict__ qp,
                                              const float* __restrict__ kp,
                                              const float* __restrict__ w1,
                                              const float* __restrict__ rb1,
                                              const float* __restrict__ w2,
                                              const float* __restrict__ rb2,
                                              float* __restrict__ aout) {
    __shared__ float w3s[DHh * DHh];
    __shared__ float qi[DHh], qpi[DHh], rb1s[DHh], w2s[DHh];
    __shared__ float sc[Cc], srt[Cc], pr[Cc];
    const int bid = blockIdx.x;             // (b*H + h)*C + i
    const int t = threadIdx.x;
    const int i = bid & 255, bh = bid >> 8; // bh = b*H + h
    const int rowbase = (bh * Cc + i) * DHh;
    for (int id2 = t; id2 < DHh * DHh; id2 += 256)
        w3s[id2] = w1[(id2 >> 5) * 96 + 64 + (id2 & 31)];
    if (t < DHh) {
        qi[t] = q[rowbase + t];
        qpi[t] = qp[rowbase + t];
        rb1s[t] = rb1[t];
        w2s[t] = w2[t];
    }
    __syncthreads();
    // --- score for column j = t ---
    const int jb = (bh * Cc + t) * DHh;
    float p[DHh];
#pragma unroll
    for (int e = 0; e < DHh; ++e) p[e] = qi[e] * k[jb + e];
    float acc = 0.f;
    for (int d = 0; d < DHh; ++d) {
        float r = qpi[d] + rb1s[d] + kp[jb + d];
        const float* wr = &w3s[d * 32];
#pragma unroll
        for (int e = 0; e < DHh; ++e) r = fmaf(p[e], wr[e], r);
        acc = fmaf(gelu_exact(r), w2s[d], acc);
    }
    const float score = (acc + rb2[0]) * 0.17677669529663689f; // 1/sqrt(32)
    sc[t] = score; srt[t] = score;
    __syncthreads();
    // --- bitonic sort (descending) to find kth largest & max ---
    for (int kk = 2; kk <= Cc; kk <<= 1) {
        for (int j2 = kk >> 1; j2 > 0; j2 >>= 1) {
            int ixj = t ^ j2;
            if (ixj > t) {
                float a = srt[t], bv = srt[ixj];
                bool desc = ((t & kk) == 0);
                if (desc ? (bv > a) : (a > bv)) { srt[t] = bv; srt[ixj] = a; }
            }
            __syncthreads();
        }
    }
    const float minv = srt[Kk - 1];
    const float mx = srt[0];
    __syncthreads();               // protect srt before reuse as reduction buffer
    float ev = (score >= minv) ? expf(score - mx) : 0.f;
    float ssum = blk_sum<256>(ev, srt, t);
    sc[t] = ev / ssum;
    __syncthreads();
    // --- attn @ v ---
    const int d = t & 31, chunk = t >> 5;
    float partial = 0.f;
    const int vb2 = (bh * Cc + chunk * 32) * DHh + d;
#pragma unroll
    for (int jj = 0; jj < 32; ++jj)
        partial = fmaf(sc[chunk * 32 + jj], v[vb2 + jj * DHh], partial);
    pr[t] = partial;
    __syncthreads();
    if (t < 32) {
        float o = pr[t];
#pragma unroll
        for (int cc2 = 1; cc2 < 8; ++cc2) o += pr[cc2 * 32 + t];
        const int b = bh >> 2, h = bh & 3;
        aout[(b * Cc + i) * DMm + h * DHh + t] = o;
    }
}

// ---------------- K5: o-proj + LN + FFN + LN (per layer) ----------------
__global__ __launch_bounds__(128) void k_ffn(const float* __restrict__ aout,
                                             const float* __restrict__ ow, const float* __restrict__ ob,
                                             const float* __restrict__ n1g, const float* __restrict__ n1b,
                                             const float* __restrict__ fw1, const float* __restrict__ fb1,
                                             const float* __restrict__ fw2, const float* __restrict__ fb2,
                                             const float* __restrict__ n2g, const float* __restrict__ n2b,
                                             float* __restrict__ bnd) {
    __shared__ float arow[DMm], b1row[DMm], ff1[4 * DMm], red[128];
    const int bc = blockIdx.x, t = threadIdx.x;
    arow[t] = aout[bc * DMm + t];
    float bv = bnd[bc * DMm + t];
    __syncthreads();
    float t1 = bv + ob[t] + dot128(arow, ow + t * DMm);
    float mean = blk_sum<128>(t1, red, t) * (1.f / 128.f);
    float d0 = t1 - mean;
    float var = blk_sum<128>(d0 * d0, red, t) * (1.f / 128.f);
    float b1v = d0 / sqrtf(var + 1e-5f) * n1g[t] + n1b[t];
    b1row[t] = b1v;
    __syncthreads();
    for (int r = 0; r < 4; ++r) {
        int o = t + r * 128;
        ff1[o] = gelu_exact(fb1[o] + dot128(b1row, fw1 + o * DMm));
    }
    __syncthreads();
    float acc = fb2[t];
    const float* wr = fw2 + t * 512;
#pragma unroll 16
    for (int e2 = 0; e2 < 512; ++e2) acc = fmaf(ff1[e2], wr[e2], acc);
    float t2 = b1v + acc;
    mean = blk_sum<128>(t2, red, t) * (1.f / 128.f);
    d0 = t2 - mean;
    var = blk_sum<128>(d0 * d0, red, t) * (1.f / 128.f);
    bnd[bc * DMm + t] = d0 / sqrtf(var + 1e-5f) * n2g[t] + n2b[t];
}

// ---------------- K6: task-query readout h ----------------
__global__ __launch_bounds__(256) void k_readout_h(const float* __restrict__ bnd,
                                                   const float* __restrict__ tq,
                                                   float* __restrict__ hbuf) {
    __shared__ float tqs[DMm], scb[Cc], red[Cc];
    const int b = blockIdx.x, t = threadIdx.x;
    if (t < DMm) tqs[t] = tq[t];
    __syncthreads();
    float s = 0.f;
    const float* br = bnd + (b * Cc + t) * DMm;
#pragma unroll 16
    for (int e = 0; e < DMm; ++e) s = fmaf(tqs[e], br[e], s);
    s *= 0.08838834764831845f; // 1/sqrt(128)
    float mx = blk_max<256>(s, red, t);
    float ev = expf(s - mx);
    float sum = blk_sum<256>(ev, red, t);
    scb[t] = ev / sum;
    __syncthreads();
    if (t < DMm) {
        float acc = 0.f;
        for (int c = 0; c < Cc; ++c) acc = fmaf(scb[c], bnd[(b * Cc + c) * DMm + t], acc);
        hbuf[b * DMm + t] = acc;
    }
}

// ---------------- K7: slots attention + GRU contrib ----------------
__global__ __launch_bounds__(256) void k_slots(const float* __restrict__ bnd,
                                               const float* __restrict__ slots,
                                               const float* __restrict__ wih,
                                               const float* __restrict__ whh,
                                               const float* __restrict__ bih,
                                               const float* __restrict__ bhh,
                                               float* __restrict__ contrib) {
    __shared__ float sl[DMm], a2[Cc], red[Cc], ctxs[DMm], giS[3 * DMm], ghS[3 * DMm];
    const int bid = blockIdx.x;
    const int b = bid >> 6, s = bid & 63;
    const int t = threadIdx.x;
    if (t < DMm) sl[t] = slots[s * DMm + t];
    __syncthreads();
    float sv = 0.f;
    const float* br = bnd + (b * Cc + t) * DMm;
#pragma unroll 16
    for (int e = 0; e < DMm; ++e) sv = fmaf(sl[e], br[e], sv);
    sv *= 0.08838834764831845f;
    float mx = blk_max<256>(sv, red, t);
    float ev = expf(sv - mx);
    float sum = blk_sum<256>(ev, red, t);
    a2[t] = ev / sum;
    __syncthreads();
    if (t < DMm) {
        float acc = 0.f;
        for (int c = 0; c < Cc; ++c) acc = fmaf(a2[c], bnd[(b * Cc + c) * DMm + t], acc);
        ctxs[t] = acc;
    }
    __syncthreads();
    giS[t] = bih[t] + dot128(ctxs, wih + t * DMm);
    ghS[t] = bhh[t] + dot128(sl, whh + t * DMm);
    if (t < DMm) {
        int o = 256 + t;
        giS[o] = bih[o] + dot128(ctxs, wih + o * DMm);
        ghS[o] = bhh[o] + dot128(sl, whh + o * DMm);
    }
    __syncthreads();
    if (t < DMm) {
        float r = 1.f / (1.f + expf(-(giS[t] + ghS[t])));
        float z = 1.f / (1.f + expf(-(giS[128 + t] + ghS[128 + t])));
        float n = tanhf(giS[256 + t] + r * ghS[256 + t]);
        contrib[(b * Ss + s) * DMm + t] = (1.f - z) * n + z * sl[t];
    }
}

// ---------------- K8: mem LN + head ----------------
__global__ __launch_bounds__(128) void k_final(const float* __restrict__ contrib,
                                               const float* __restrict__ hbuf,
                                               const float* __restrict__ mg, const float* __restrict__ mb,
                                               const float* __restrict__ hw, const float* __restrict__ hb,
                                               float* __restrict__ out) {
    __shared__ float hm[DMm], red[128];
    const int b = blockIdx.x, t = threadIdx.x;
    float acc = 0.f;
    for (int s = 0; s < Ss; ++s) acc += contrib[(b * Ss + s) * DMm + t];
    acc *= (1.f / (float)Ss);
    float mean = blk_sum<128>(acc, red, t) * (1.f / 128.f);
    float d0 = acc - mean;
    float var = blk_sum<128>(d0 * d0, red, t) * (1.f / 128.f);
    float memv = d0 / sqrtf(var + 1e-5f) * mg[t] + mb[t];
    hm[t] = hbuf[b * DMm + t] + memv;
    __syncthreads();
    if (t < OUTn) {
        float o = hb[t];
        const float* wr = hw + t * DMm;
#pragma unroll 16
        for (int e = 0; e < DMm; ++e) o = fmaf(hm[e], wr[e], o);
        out[b * OUTn + t] = o;
    }
}

extern "C" void kernel_launch(void* const* d_in, const int* in_sizes, int n_in,
                              void* d_out, int out_size, void* d_ws, size_t ws_size,
                              hipStream_t stream) {
    const float* x         = (const float*)d_in[0];
    const float* emb_roles = (const float*)d_in[1];
    const float* filler_w  = (const float*)d_in[2];
    const float* conv_w    = (const float*)d_in[3];
    const float* conv_b    = (const float*)d_in[4];
    const float* outer_w   = (const float*)d_in[5];
    const float* enc_ng    = (const float*)d_in[6];
    const float* enc_nb    = (const float*)d_in[7];
    const float* qw        = (const float*)d_in[8];
    const float* qb        = (const float*)d_in[9];
    const float* kw        = (const float*)d_in[10];
    const float* kb        = (const float*)d_in[11];
    const float* vw        = (const float*)d_in[12];
    const float* vb        = (const float*)d_in[13];
    const float* rel_w1    = (const float*)d_in[14];
    const float* rel_b1    = (const float*)d_in[15];
    const float* rel_w2    = (const float*)d_in[16];
    const float* rel_b2    = (const float*)d_in[17];
    const float* ow        = (const float*)d_in[18];
    const float* ob        = (const float*)d_in[19];
    const float* n1g       = (const float*)d_in[20];
    const float* n1b       = (const float*)d_in[21];
    const float* n2g       = (const float*)d_in[22];
    const float* n2b       = (const float*)d_in[23];
    const float* ffn_w1    = (const float*)d_in[24];
    const float* ffn_b1    = (const float*)d_in[25];
    const float* ffn_w2    = (const float*)d_in[26];
    const float* ffn_b2    = (const float*)d_in[27];
    const float* task_q    = (const float*)d_in[28];
    const float* slots     = (const float*)d_in[29];
    const float* gru_wih   = (const float*)d_in[30];
    const float* gru_whh   = (const float*)d_in[31];
    const float* gru_bih   = (const float*)d_in[32];
    const float* gru_bhh   = (const float*)d_in[33];
    const float* mem_ng    = (const float*)d_in[34];
    const float* mem_nb    = (const float*)d_in[35];
    const float* head_w    = (const float*)d_in[36];
    const float* head_b    = (const float*)d_in[37];

    float* ws = (float*)d_ws;
    const int BC = Bb * Cc;                 // 512
    const int BHCD = Bb * Hh * Cc * DHh;    // 65536
    float* valsb = ws;                      // 512
    float* mzb   = valsb + BC;              // 512
    float* bnd   = mzb + BC;                // 65536
    float* qB    = bnd + BC * DMm;
    float* kB    = qB + BHCD;
    float* vB    = kB + BHCD;
    float* qpB   = vB + BHCD;
    float* kpB   = qpB + BHCD;
    float* aout  = kpB + BHCD;              // 65536
    float* hbuf  = aout + BC * DMm;         // 256
    float* contrib = hbuf + Bb * DMm;       // 16384

    k_topk<<<Bb, 1024, 0, stream>>>(x, valsb, mzb);
    k_encode<<<BC, 128, 0, stream>>>(valsb, mzb, emb_roles, filler_w, conv_w, conv_b,
                                     outer_w, enc_ng, enc_nb, bnd);
    for (int l = 0; l < Ll; ++l) {
        k_qkv<<<BC, 128, 0, stream>>>(bnd,
                                      qw + l * DMm * DMm, qb + l * DMm,
                                      kw + l * DMm * DMm, kb + l * DMm,
                                      vw + l * DMm * DMm, vb + l * DMm,
                                      rel_w1 + l * DHh * 3 * DHh,
                                      qB, kB, vB, qpB, kpB);
        k_attn<<<Bb * Hh * Cc, 256, 0, stream>>>(qB, kB, vB, qpB, kpB,
                                                 rel_w1 + l * DHh * 3 * DHh,
                                                 rel_b1 + l * DHh,
                                                 rel_w2 + l * DHh,
                                                 rel_b2 + l,
                                                 aout);
        k_ffn<<<BC, 128, 0, stream>>>(aout,
                                      ow + l * DMm * DMm, ob + l * DMm,
                                      n1g + l * DMm, n1b + l * DMm,
                                      ffn_w1 + l * 4 * DMm * DMm, ffn_b1 + l * 4 * DMm,
                                      ffn_w2 + l * 4 * DMm * DMm, ffn_b2 + l * DMm,
                                      n2g + l * DMm, n2b + l * DMm,
                                      bnd);
    }
    k_readout_h<<<Bb, 256, 0, stream>>>(bnd, task_q, hbuf);
    k_slots<<<Bb * Ss, 256, 0, stream>>>(bnd, slots, gru_wih, gru_whh, gru_bih, gru_bhh, contrib);
    k_final<<<Bb, 128, 0, stream>>>(contrib, hbuf, mem_ng, mem_nb, head_w, head_b, (float*)d_out);
}

// Round 4
// 546.430 us; speedup vs baseline: 1.1532x; 1.1532x over previous
//
#include <hip/hip_runtime.h>
#include <hip/hip_bf16.h>
#include <math.h>

// dims
#define Bb 2
#define Nn 2048
#define Cc 256
#define Kk 64
#define Hh 4
#define DHh 32
#define DMm 128
#define DIi 16
#define Ll 3
#define Ss 64
#define OUTn 10

__device__ __forceinline__ float gelu_exact(float x) {
    return 0.5f * x * (1.0f + erff(x * 0.70710678118654752f));
}

// 128-dot with 4 interleaved accumulator chains (contiguous, vectorizable)
__device__ __forceinline__ float dot128_4(const float* a, const float* __restrict__ w) {
    float s0 = 0.f, s1 = 0.f, s2 = 0.f, s3 = 0.f;
#pragma unroll
    for (int e = 0; e < 128; e += 4) {
        s0 = fmaf(a[e],     w[e],     s0);
        s1 = fmaf(a[e + 1], w[e + 1], s1);
        s2 = fmaf(a[e + 2], w[e + 2], s2);
        s3 = fmaf(a[e + 3], w[e + 3], s3);
    }
    return (s0 + s1) + (s2 + s3);
}

template<int NT>
__device__ __forceinline__ float blk_sum(float v, float* red, int t) {
    red[t] = v; __syncthreads();
#pragma unroll
    for (int s = NT >> 1; s > 0; s >>= 1) {
        if (t < s) red[t] += red[t + s];
        __syncthreads();
    }
    float r = red[0];
    __syncthreads();
    return r;
}

template<int NT>
__device__ __forceinline__ float blk_max(float v, float* red, int t) {
    red[t] = v; __syncthreads();
#pragma unroll
    for (int s = NT >> 1; s > 0; s >>= 1) {
        if (t < s) red[t] = fmaxf(red[t], red[t + s]);
        __syncthreads();
    }
    float r = red[0];
    __syncthreads();
    return r;
}

// ---------------- K1: top-k (full bitonic sort of 2048, descending, tie -> lower idx) --------
__global__ __launch_bounds__(1024) void k_topk(const float* __restrict__ x,
                                               float* __restrict__ vals,
                                               float* __restrict__ mz) {
    __shared__ float key[Nn];
    __shared__ int   idx[Nn];
    const int b = blockIdx.x, t = threadIdx.x;
    for (int i = t; i < Nn; i += 1024) { key[i] = x[b * Nn + i]; idx[i] = i; }
    __syncthreads();
    for (int k = 2; k <= Nn; k <<= 1) {
        for (int j = k >> 1; j > 0; j >>= 1) {
            for (int i = t; i < Nn; i += 1024) {
                int ixj = i ^ j;
                if (ixj > i) {
                    float va = key[i], vb = key[ixj];
                    int ia = idx[i], ib = idx[ixj];
                    bool aG = (va > vb) || (va == vb && ia < ib);
                    bool desc = ((i & k) == 0);
                    bool dosw = desc ? (!aG) : aG;
                    if (dosw) { key[i] = vb; key[ixj] = va; idx[i] = ib; idx[ixj] = ia; }
                }
            }
            __syncthreads();
        }
    }
    if (t < Cc) {
        vals[b * Cc + t] = log1pf(fmaxf(key[t], 0.f));
        mz[b * Cc + t] = (float)idx[t];
    }
}

// ---------------- K2: binding encoder (256 thr, 2-way split dot) ----------------
__global__ __launch_bounds__(256) void k_encode(const float* __restrict__ vals,
                                                const float* __restrict__ mz,
                                                const float* __restrict__ emb_roles,
                                                const float* __restrict__ filler_w,
                                                const float* __restrict__ conv_w,
                                                const float* __restrict__ conv_b,
                                                const float* __restrict__ outer_w,
                                                const float* __restrict__ g,
                                                const float* __restrict__ bb,
                                                float* __restrict__ bnd) {
    __shared__ float roles[DIi], fill[DIi], outerv[256], ps[2][128], red[256];
    const int bc = blockIdx.x;
    const int b = bc >> 8, c = bc & 255;
    const int t = threadIdx.x;
    const float NEG = -1.3157629102823120f; // -ln(10000)/7
    if (t < DIi) {
        float mzv = mz[bc];
        float rr;
        if (t < 8) rr = sinf(mzv * expf((float)t * NEG));
        else       rr = cosf(mzv * expf((float)(t - 8) * NEG));
        roles[t] = rr + emb_roles[c * DIi + t];
    } else if (t < 2 * DIi) {
        int e = t - DIi;
        float vc = vals[bc];
        float fp = vc * filler_w[e];
        float acc = conv_b[e];
#pragma unroll
        for (int kk = 0; kk < 5; ++kk) {
            int pos = c - 2 + kk;
            pos = pos < 0 ? -pos : (pos >= Cc ? 2 * Cc - 2 - pos : pos);
            acc = fmaf(vals[b * Cc + pos], conv_w[e * 5 + kk], acc);
        }
        fill[e] = gelu_exact(fp + gelu_exact(acc));
    }
    __syncthreads();
    outerv[t] = roles[t >> 4] * fill[t & 15];
    __syncthreads();
    const int o = t & 127, seg = t >> 7;
    const float* wrow = outer_w + o * 256 + seg * 128;
    const float* ov = outerv + seg * 128;
    float acc = dot128_4(ov, wrow);
    ps[seg][o] = acc; __syncthreads();
    float t1 = 0.f;
    if (t < 128) t1 = ps[0][t] + ps[1][t];
    float mean = blk_sum<256>(t < 128 ? t1 : 0.f, red, t) * (1.f / 128.f);
    float d0 = t1 - mean;
    float var = blk_sum<256>(t < 128 ? d0 * d0 : 0.f, red, t) * (1.f / 128.f);
    if (t < 128) bnd[bc * DMm + t] = d0 / sqrtf(var + 1e-5f) * g[t] + bb[t];
}

// ---------------- K3: QKV + qp/kp (blocks split by which in {q,k,v}) ----------------
__global__ __launch_bounds__(128) void k_qkv(const float* __restrict__ bnd,
                                             const float* __restrict__ qw, const float* __restrict__ qb,
                                             const float* __restrict__ kw, const float* __restrict__ kb,
                                             const float* __restrict__ vw, const float* __restrict__ vb,
                                             const float* __restrict__ w1,
                                             float* __restrict__ q, float* __restrict__ k,
                                             float* __restrict__ v, float* __restrict__ qp,
                                             float* __restrict__ kp) {
    __shared__ float brow[DMm], prow[DMm];
    const int bid = blockIdx.x;
    const int which = bid >> 9;      // 0:q 1:k 2:v
    const int bc = bid & 511;
    const int b = bc >> 8, c = bc & 255;
    const int t = threadIdx.x;
    brow[t] = bnd[bc * DMm + t];
    __syncthreads();
    const float* w  = (which == 0) ? qw : (which == 1) ? kw : vw;
    const float* bi = (which == 0) ? qb : (which == 1) ? kb : vb;
    float val = bi[t] + dot128_4(brow, w + t * DMm);
    const int h = t >> 5, d = t & 31;
    const int gi = ((b * Hh + h) * Cc + c) * DHh + d;
    float* outp = (which == 0) ? q : (which == 1) ? k : v;
    outp[gi] = val;
    if (which < 2) {
        prow[t] = val;
        __syncthreads();
        const float* wr = w1 + d * 96 + ((which == 1) ? 32 : 0);
        float acc = 0.f;
#pragma unroll
        for (int e = 0; e < DHh; ++e) acc = fmaf(prow[h * 32 + e], wr[e], acc);
        ((which == 0) ? qp : kp)[gi] = acc;
    }
}

// ---------------- K4: wave-per-row attention (no barriers in hot path) ----------------
__global__ __launch_bounds__(64) void k_attn(const float* __restrict__ q,
                                             const float* __restrict__ k,
                                             const float* __restrict__ v,
                                             const float* __restrict__ qp,
                                             const float* __restrict__ kp,
                                             const float* __restrict__ w1,
                                             const float* __restrict__ rb1,
                                             const float* __restrict__ w2,
                                             const float* __restrict__ rb2,
                                             float* __restrict__ aout) {
    __shared__ float w3s[DHh * DHh];
    __shared__ float qs[DHh], qps[DHh], rb1s[DHh], w2s[DHh];
    __shared__ float aw[Cc];
    const int bid = blockIdx.x;          // bh*256 + i
    const int t = threadIdx.x;           // lane 0..63
    const int i = bid & 255, bh = bid >> 8;
    const int rowbase = (bh * Cc + i) * DHh;

    // stage w3 (1024 floats) via coalesced float4
#pragma unroll
    for (int m = 0; m < 4; ++m) {
        int f = t + 64 * m;              // float4 id 0..255
        int row = f >> 3, c4 = f & 7;
        float4 vv = *reinterpret_cast<const float4*>(w1 + row * 96 + 64 + c4 * 4);
        *reinterpret_cast<float4*>(&w3s[row * 32 + c4 * 4]) = vv;
    }
    if (t < 32) {
        qs[t]   = q[rowbase + t];
        qps[t]  = qp[rowbase + t];
        rb1s[t] = rb1[t];
        w2s[t]  = w2[t];
    }
    __syncthreads();
    const float rb2v = rb2[0];

    float sc4[4];
    for (int r = 0; r < 4; ++r) {
        const int j = r * 64 + t;
        const int jb = (bh * Cc + j) * DHh;
        float kr[32], kpr[32];
        const float4* k4  = reinterpret_cast<const float4*>(k + jb);
        const float4* kp4 = reinterpret_cast<const float4*>(kp + jb);
#pragma unroll
        for (int m = 0; m < 8; ++m) {
            float4 a = k4[m];  kr[4*m] = a.x; kr[4*m+1] = a.y; kr[4*m+2] = a.z; kr[4*m+3] = a.w;
            float4 bq = kp4[m]; kpr[4*m] = bq.x; kpr[4*m+1] = bq.y; kpr[4*m+2] = bq.z; kpr[4*m+3] = bq.w;
        }
        float p[32];
#pragma unroll
        for (int e = 0; e < 32; ++e) p[e] = qs[e] * kr[e];
        float acc = 0.f;
#pragma unroll 4
        for (int d = 0; d < 32; ++d) {
            const float* wr = &w3s[d * 32];
            float r0 = qps[d] + rb1s[d] + kpr[d], r1 = 0.f, r2 = 0.f, r3 = 0.f;
#pragma unroll
            for (int e = 0; e < 8; ++e) {
                r0 = fmaf(p[e],      wr[e],      r0);
                r1 = fmaf(p[8 + e],  wr[8 + e],  r1);
                r2 = fmaf(p[16 + e], wr[16 + e], r2);
                r3 = fmaf(p[24 + e], wr[24 + e], r3);
            }
            float rr = (r0 + r1) + (r2 + r3);
            acc = fmaf(gelu_exact(rr), w2s[d], acc);
        }
        sc4[r] = (acc + rb2v) * 0.17677669529663689f; // 1/sqrt(32)
    }

    // --- wave bitonic sort, 256 elems descending; idx = r*64 + lane ---
    float v0 = sc4[0], v1 = sc4[1], v2 = sc4[2], v3 = sc4[3];
    auto cx_lane = [&](int k_, int j_) {
        float o0 = __shfl_xor(v0, j_), o1 = __shfl_xor(v1, j_);
        float o2 = __shfl_xor(v2, j_), o3 = __shfl_xor(v3, j_);
        bool lower = ((t & j_) == 0);
        bool d0 = (((0 * 64 + t) & k_) == 0);
        bool d1 = (((1 * 64 + t) & k_) == 0);
        bool d2 = (((2 * 64 + t) & k_) == 0);
        bool d3 = (((3 * 64 + t) & k_) == 0);
        v0 = (lower == d0) ? fmaxf(v0, o0) : fminf(v0, o0);
        v1 = (lower == d1) ? fmaxf(v1, o1) : fminf(v1, o1);
        v2 = (lower == d2) ? fmaxf(v2, o2) : fminf(v2, o2);
        v3 = (lower == d3) ? fmaxf(v3, o3) : fminf(v3, o3);
    };
    auto cx_reg1 = [&](int k_) { // j=64: pairs (0,1),(2,3)
        bool dA = (((0 * 64) & k_) == 0);
        bool dB = (((2 * 64) & k_) == 0);
        float aA = v0, bA = v1;
        v0 = dA ? fmaxf(aA, bA) : fminf(aA, bA);
        v1 = dA ? fminf(aA, bA) : fmaxf(aA, bA);
        float aB = v2, bB = v3;
        v2 = dB ? fmaxf(aB, bB) : fminf(aB, bB);
        v3 = dB ? fminf(aB, bB) : fmaxf(aB, bB);
    };
    auto cx_reg2 = [&](int k_) { // j=128: pairs (0,2),(1,3)
        bool dA = (((0 * 64) & k_) == 0);
        bool dB = (((1 * 64) & k_) == 0);
        float aA = v0, bA = v2;
        v0 = dA ? fmaxf(aA, bA) : fminf(aA, bA);
        v2 = dA ? fminf(aA, bA) : fmaxf(aA, bA);
        float aB = v1, bB = v3;
        v1 = dB ? fmaxf(aB, bB) : fminf(aB, bB);
        v3 = dB ? fminf(aB, bB) : fmaxf(aB, bB);
    };
    cx_lane(2, 1);
    cx_lane(4, 2); cx_lane(4, 1);
    cx_lane(8, 4); cx_lane(8, 2); cx_lane(8, 1);
    cx_lane(16, 8); cx_lane(16, 4); cx_lane(16, 2); cx_lane(16, 1);
    cx_lane(32, 16); cx_lane(32, 8); cx_lane(32, 4); cx_lane(32, 2); cx_lane(32, 1);
    cx_lane(64, 32); cx_lane(64, 16); cx_lane(64, 8); cx_lane(64, 4); cx_lane(64, 2); cx_lane(64, 1);
    cx_reg1(128);
    cx_lane(128, 32); cx_lane(128, 16); cx_lane(128, 8); cx_lane(128, 4); cx_lane(128, 2); cx_lane(128, 1);
    cx_reg2(256); cx_reg1(256);
    cx_lane(256, 32); cx_lane(256, 16); cx_lane(256, 8); cx_lane(256, 4); cx_lane(256, 2); cx_lane(256, 1);

    const float minv = __shfl(v0, 63);
    const float mx   = __shfl(v0, 0);

    // --- masked softmax (wave butterfly) ---
    float ev[4], lsum = 0.f;
#pragma unroll
    for (int r = 0; r < 4; ++r) {
        ev[r] = (sc4[r] >= minv) ? expf(sc4[r] - mx) : 0.f;
        lsum += ev[r];
    }
#pragma unroll
    for (int off = 1; off < 64; off <<= 1) lsum += __shfl_xor(lsum, off);
    const float inv = 1.f / lsum;
#pragma unroll
    for (int r = 0; r < 4; ++r) aw[r * 64 + t] = ev[r] * inv;
    __syncthreads();

    // --- attn @ v: lane covers (d = t&31, half = t>>5), 128 j's each ---
    const int d = t & 31, half = t >> 5;
    const float* vb = v + (bh * Cc + half * 128) * DHh + d;
    const float* awh = aw + half * 128;
    float a0 = 0.f, a1 = 0.f, a2 = 0.f, a3 = 0.f;
#pragma unroll 8
    for (int jj = 0; jj < 32; ++jj) {
        a0 = fmaf(awh[jj],      vb[jj * 32],        a0);
        a1 = fmaf(awh[32 + jj], vb[(32 + jj) * 32], a1);
        a2 = fmaf(awh[64 + jj], vb[(64 + jj) * 32], a2);
        a3 = fmaf(awh[96 + jj], vb[(96 + jj) * 32], a3);
    }
    float accv = (a0 + a1) + (a2 + a3);
    accv += __shfl_xor(accv, 32);
    if (t < 32) {
        const int b = bh >> 2, h = bh & 3;
        aout[(b * Cc + i) * DMm + h * DHh + t] = accv;
    }
}

// ---------------- K5: o-proj + LN + FFN + LN (512 threads, split dots) ----------------
__global__ __launch_bounds__(512) void k_ffn(const float* __restrict__ aout,
                                             const float* __restrict__ ow, const float* __restrict__ ob,
                                             const float* __restrict__ n1g, const float* __restrict__ n1b,
                                             const float* __restrict__ fw1, const float* __restrict__ fb1,
                                             const float* __restrict__ fw2, const float* __restrict__ fb2,
                                             const float* __restrict__ n2g, const float* __restrict__ n2b,
                                             float* __restrict__ bnd) {
    __shared__ float arow[DMm], b1row[DMm], ff1[512], ps[4][128], red[512];
    const int bc = blockIdx.x, t = threadIdx.x;
    if (t < 128) arow[t] = aout[bc * DMm + t];
    __syncthreads();
    const int o = t & 127, seg = t >> 7;
    {   // oproj: 4-way split over 32-chunks
        const float* wr = ow + o * DMm + seg * 32;
        const float* ar = arow + seg * 32;
        float pa = 0.f;
#pragma unroll
        for (int e = 0; e < 32; ++e) pa = fmaf(ar[e], wr[e], pa);
        ps[seg][o] = pa;
    }
    __syncthreads();
    float t1 = 0.f;
    if (t < 128) t1 = bnd[bc * DMm + t] + ob[t] + ((ps[0][t] + ps[1][t]) + (ps[2][t] + ps[3][t]));
    float mean = blk_sum<512>(t < 128 ? t1 : 0.f, red, t) * (1.f / 128.f);
    float d0 = t1 - mean;
    float var = blk_sum<512>(t < 128 ? d0 * d0 : 0.f, red, t) * (1.f / 128.f);
    if (t < 128) b1row[t] = d0 / sqrtf(var + 1e-5f) * n1g[t] + n1b[t];
    __syncthreads();
    // ffn1: one 128-dot per thread (512 outputs)
    ff1[t] = gelu_exact(fb1[t] + dot128_4(b1row, fw1 + t * DMm));
    __syncthreads();
    {   // ffn2: 4-way split over 128-chunks
        const float* wr = fw2 + o * 512 + seg * 128;
        const float* fr = ff1 + seg * 128;
        float pb = dot128_4(fr, wr);
        ps[seg][o] = pb;
    }
    __syncthreads();
    float t2 = 0.f;
    if (t < 128) t2 = b1row[t] + fb2[t] + ((ps[0][t] + ps[1][t]) + (ps[2][t] + ps[3][t]));
    mean = blk_sum<512>(t < 128 ? t2 : 0.f, red, t) * (1.f / 128.f);
    d0 = t2 - mean;
    var = blk_sum<512>(t < 128 ? d0 * d0 : 0.f, red, t) * (1.f / 128.f);
    if (t < 128) bnd[bc * DMm + t] = d0 / sqrtf(var + 1e-5f) * n2g[t] + n2b[t];
}

// ---------------- K6+K7 fused: slots GRU (s<64) and task-query readout (s==64) -------------
__global__ __launch_bounds__(256) void k_slots(const float* __restrict__ bnd,
                                               const float* __restrict__ slots,
                                               const float* __restrict__ tq,
                                               const float* __restrict__ wih,
                                               const float* __restrict__ whh,
                                               const float* __restrict__ bih,
                                               const float* __restrict__ bhh,
                                               float* __restrict__ contrib,
                                               float* __restrict__ hbuf) {
    __shared__ float sl[DMm], a2[Cc], red[Cc], ctx2[2][128], ctxs[DMm], giS[3 * DMm], ghS[3 * DMm];
    const int bid = blockIdx.x;
    const int b = bid / 65, s = bid % 65;
    const int t = threadIdx.x;
    if (t < DMm) sl[t] = (s < Ss) ? slots[s * DMm + t] : tq[t];
    __syncthreads();
    float sv = dot128_4(sl, bnd + (b * Cc + t) * DMm) * 0.08838834764831845f;
    float mxv = blk_max<256>(sv, red, t);
    float ev = expf(sv - mxv);
    float sum = blk_sum<256>(ev, red, t);
    a2[t] = ev / sum;
    __syncthreads();
    {   // ctx: 2-way split over c
        const int o = t & 127, seg = t >> 7;
        float cacc = 0.f;
        for (int cc = 0; cc < 128; ++cc) {
            int c = seg * 128 + cc;
            cacc = fmaf(a2[c], bnd[(b * Cc + c) * DMm + o], cacc);
        }
        ctx2[seg][o] = cacc;
    }
    __syncthreads();
    if (t < DMm) ctxs[t] = ctx2[0][t] + ctx2[1][t];
    __syncthreads();
    if (s == Ss) {
        if (t < DMm) hbuf[b * DMm + t] = ctxs[t];
        return;
    }
    giS[t] = bih[t] + dot128_4(ctxs, wih + t * DMm);
    ghS[t] = bhh[t] + dot128_4(sl, whh + t * DMm);
    if (t < DMm) {
        int o = 256 + t;
        giS[o] = bih[o] + dot128_4(ctxs, wih + o * DMm);
        ghS[o] = bhh[o] + dot128_4(sl, whh + o * DMm);
    }
    __syncthreads();
    if (t < DMm) {
        float r = 1.f / (1.f + expf(-(giS[t] + ghS[t])));
        float z = 1.f / (1.f + expf(-(giS[128 + t] + ghS[128 + t])));
        float n = tanhf(giS[256 + t] + r * ghS[256 + t]);
        contrib[(b * Ss + s) * DMm + t] = (1.f - z) * n + z * sl[t];
    }
}

// ---------------- K8: mem LN + head ----------------
__global__ __launch_bounds__(128) void k_final(const float* __restrict__ contrib,
                                               const float* __restrict__ hbuf,
                                               const float* __restrict__ mg, const float* __restrict__ mb,
                                               const float* __restrict__ hw, const float* __restrict__ hb,
                                               float* __restrict__ out) {
    __shared__ float hm[DMm], red[128];
    const int b = blockIdx.x, t = threadIdx.x;
    float acc = 0.f;
    for (int s = 0; s < Ss; ++s) acc += contrib[(b * Ss + s) * DMm + t];
    acc *= (1.f / (float)Ss);
    float mean = blk_sum<128>(acc, red, t) * (1.f / 128.f);
    float d0 = acc - mean;
    float var = blk_sum<128>(d0 * d0, red, t) * (1.f / 128.f);
    float memv = d0 / sqrtf(var + 1e-5f) * mg[t] + mb[t];
    hm[t] = hbuf[b * DMm + t] + memv;
    __syncthreads();
    if (t < OUTn) {
        float o = hb[t];
        const float* wr = hw + t * DMm;
#pragma unroll 16
        for (int e = 0; e < DMm; ++e) o = fmaf(hm[e], wr[e], o);
        out[b * OUTn + t] = o;
    }
}

extern "C" void kernel_launch(void* const* d_in, const int* in_sizes, int n_in,
                              void* d_out, int out_size, void* d_ws, size_t ws_size,
                              hipStream_t stream) {
    const float* x         = (const float*)d_in[0];
    const float* emb_roles = (const float*)d_in[1];
    const float* filler_w  = (const float*)d_in[2];
    const float* conv_w    = (const float*)d_in[3];
    const float* conv_b    = (const float*)d_in[4];
    const float* outer_w   = (const float*)d_in[5];
    const float* enc_ng    = (const float*)d_in[6];
    const float* enc_nb    = (const float*)d_in[7];
    const float* qw        = (const float*)d_in[8];
    const float* qb        = (const float*)d_in[9];
    const float* kw        = (const float*)d_in[10];
    const float* kb        = (const float*)d_in[11];
    const float* vw        = (const float*)d_in[12];
    const float* vb        = (const float*)d_in[13];
    const float* rel_w1    = (const float*)d_in[14];
    const float* rel_b1    = (const float*)d_in[15];
    const float* rel_w2    = (const float*)d_in[16];
    const float* rel_b2    = (const float*)d_in[17];
    const float* ow        = (const float*)d_in[18];
    const float* ob        = (const float*)d_in[19];
    const float* n1g       = (const float*)d_in[20];
    const float* n1b       = (const float*)d_in[21];
    const float* n2g       = (const float*)d_in[22];
    const float* n2b       = (const float*)d_in[23];
    const float* ffn_w1    = (const float*)d_in[24];
    const float* ffn_b1    = (const float*)d_in[25];
    const float* ffn_w2    = (const float*)d_in[26];
    const float* ffn_b2    = (const float*)d_in[27];
    const float* task_q    = (const float*)d_in[28];
    const float* slots     = (const float*)d_in[29];
    const float* gru_wih   = (const float*)d_in[30];
    const float* gru_whh   = (const float*)d_in[31];
    const float* gru_bih   = (const float*)d_in[32];
    const float* gru_bhh   = (const float*)d_in[33];
    const float* mem_ng    = (const float*)d_in[34];
    const float* mem_nb    = (const float*)d_in[35];
    const float* head_w    = (const float*)d_in[36];
    const float* head_b    = (const float*)d_in[37];

    float* ws = (float*)d_ws;
    const int BC = Bb * Cc;                 // 512
    const int BHCD = Bb * Hh * Cc * DHh;    // 65536
    float* valsb = ws;                      // 512
    float* mzb   = valsb + BC;              // 512
    float* bnd   = mzb + BC;                // 65536
    float* qB    = bnd + BC * DMm;
    float* kB    = qB + BHCD;
    float* vB    = kB + BHCD;
    float* qpB   = vB + BHCD;
    float* kpB   = qpB + BHCD;
    float* aout  = kpB + BHCD;              // 65536
    float* hbuf  = aout + BC * DMm;         // 256
    float* contrib = hbuf + Bb * DMm;       // 16384

    k_topk<<<Bb, 1024, 0, stream>>>(x, valsb, mzb);
    k_encode<<<BC, 256, 0, stream>>>(valsb, mzb, emb_roles, filler_w, conv_w, conv_b,
                                     outer_w, enc_ng, enc_nb, bnd);
    for (int l = 0; l < Ll; ++l) {
        k_qkv<<<3 * BC, 128, 0, stream>>>(bnd,
                                          qw + l * DMm * DMm, qb + l * DMm,
                                          kw + l * DMm * DMm, kb + l * DMm,
                                          vw + l * DMm * DMm, vb + l * DMm,
                                          rel_w1 + l * DHh * 3 * DHh,
                                          qB, kB, vB, qpB, kpB);
        k_attn<<<Bb * Hh * Cc, 64, 0, stream>>>(qB, kB, vB, qpB, kpB,
                                                rel_w1 + l * DHh * 3 * DHh,
                                                rel_b1 + l * DHh,
                                                rel_w2 + l * DHh,
                                                rel_b2 + l,
                                                aout);
        k_ffn<<<BC, 512, 0, stream>>>(aout,
                                      ow + l * DMm * DMm, ob + l * DMm,
                                      n1g + l * DMm, n1b + l * DMm,
                                      ffn_w1 + l * 4 * DMm * DMm, ffn_b1 + l * 4 * DMm,
                                      ffn_w2 + l * 4 * DMm * DMm, ffn_b2 + l * DMm,
                                      n2g + l * DMm, n2b + l * DMm,
                                      bnd);
    }
    k_slots<<<Bb * (Ss + 1), 256, 0, stream>>>(bnd, slots, task_q, gru_wih, gru_whh,
                                               gru_bih, gru_bhh, contrib, hbuf);
    k_final<<<Bb, 128, 0, stream>>>(contrib, hbuf, mem_ng, mem_nb, head_w, head_b, (float*)d_out);
}

// Round 6
// 498.218 us; speedup vs baseline: 1.2648x; 1.0968x over previous
//
#include <hip/hip_runtime.h>
#include <hip/hip_bf16.h>
#include <math.h>

// dims
#define Bb 2
#define Nn 2048
#define Cc 256
#define Kk 64
#define Hh 4
#define DHh 32
#define DMm 128
#define DIi 16
#define Ll 3
#define Ss 64
#define OUTn 10

__device__ __forceinline__ float gelu_exact(float x) {
    return 0.5f * x * (1.0f + erff(x * 0.70710678118654752f));
}

// 128-dot with 4 interleaved accumulator chains
__device__ __forceinline__ float dot128_4(const float* a, const float* __restrict__ w) {
    float s0 = 0.f, s1 = 0.f, s2 = 0.f, s3 = 0.f;
#pragma unroll
    for (int e = 0; e < 128; e += 4) {
        s0 = fmaf(a[e],     w[e],     s0);
        s1 = fmaf(a[e + 1], w[e + 1], s1);
        s2 = fmaf(a[e + 2], w[e + 2], s2);
        s3 = fmaf(a[e + 3], w[e + 3], s3);
    }
    return (s0 + s1) + (s2 + s3);
}

// ---------------- K1: top-k (full bitonic sort of 2048, descending, tie -> lower idx) --------
__global__ __launch_bounds__(1024) void k_topk(const float* __restrict__ x,
                                               float* __restrict__ vals,
                                               float* __restrict__ mz) {
    __shared__ float key[Nn];
    __shared__ int   idx[Nn];
    const int b = blockIdx.x, t = threadIdx.x;
    for (int i = t; i < Nn; i += 1024) { key[i] = x[b * Nn + i]; idx[i] = i; }
    __syncthreads();
    for (int k = 2; k <= Nn; k <<= 1) {
        for (int j = k >> 1; j > 0; j >>= 1) {
            for (int i = t; i < Nn; i += 1024) {
                int ixj = i ^ j;
                if (ixj > i) {
                    float va = key[i], vb = key[ixj];
                    int ia = idx[i], ib = idx[ixj];
                    bool aG = (va > vb) || (va == vb && ia < ib);
                    bool desc = ((i & k) == 0);
                    bool dosw = desc ? (!aG) : aG;
                    if (dosw) { key[i] = vb; key[ixj] = va; idx[i] = ib; idx[ixj] = ia; }
                }
            }
            __syncthreads();
        }
    }
    if (t < Cc) {
        vals[b * Cc + t] = log1pf(fmaxf(key[t], 0.f));
        mz[b * Cc + t] = (float)idx[t];
    }
}

// ---------------- K2: binding encoder (256 thr, fast LN reduction) ----------------
__global__ __launch_bounds__(256) void k_encode(const float* __restrict__ vals,
                                                const float* __restrict__ mz,
                                                const float* __restrict__ emb_roles,
                                                const float* __restrict__ filler_w,
                                                const float* __restrict__ conv_w,
                                                const float* __restrict__ conv_b,
                                                const float* __restrict__ outer_w,
                                                const float* __restrict__ g,
                                                const float* __restrict__ bb,
                                                float* __restrict__ bnd) {
    __shared__ float roles[DIi], fill[DIi], outerv[256], ps[2][128];
    __shared__ float redA[4], redB[4];
    const int bc = blockIdx.x;
    const int b = bc >> 8, c = bc & 255;
    const int t = threadIdx.x;
    const float NEG = -1.3157629102823120f; // -ln(10000)/7
    if (t < DIi) {
        float mzv = mz[bc];
        float rr;
        if (t < 8) rr = sinf(mzv * expf((float)t * NEG));
        else       rr = cosf(mzv * expf((float)(t - 8) * NEG));
        roles[t] = rr + emb_roles[c * DIi + t];
    } else if (t < 2 * DIi) {
        int e = t - DIi;
        float vc = vals[bc];
        float fp = vc * filler_w[e];
        float acc = conv_b[e];
#pragma unroll
        for (int kk = 0; kk < 5; ++kk) {
            int pos = c - 2 + kk;
            pos = pos < 0 ? -pos : (pos >= Cc ? 2 * Cc - 2 - pos : pos);
            acc = fmaf(vals[b * Cc + pos], conv_w[e * 5 + kk], acc);
        }
        fill[e] = gelu_exact(fp + gelu_exact(acc));
    }
    __syncthreads();
    outerv[t] = roles[t >> 4] * fill[t & 15];
    __syncthreads();
    const int o = t & 127, seg = t >> 7;
    float acc = dot128_4(outerv + seg * 128, outer_w + o * 256 + seg * 128);
    ps[seg][o] = acc;
    __syncthreads();
    float t1 = 0.f;
    if (t < 128) t1 = ps[0][t] + ps[1][t];
    float sa = (t < 128) ? t1 : 0.f, sb = (t < 128) ? t1 * t1 : 0.f;
#pragma unroll
    for (int off = 1; off < 64; off <<= 1) { sa += __shfl_xor(sa, off); sb += __shfl_xor(sb, off); }
    if ((t & 63) == 0) { redA[t >> 6] = sa; redB[t >> 6] = sb; }
    __syncthreads();
    float S = (redA[0] + redA[1]) + (redA[2] + redA[3]);
    float Q = (redB[0] + redB[1]) + (redB[2] + redB[3]);
    float mean = S * (1.f / 128.f);
    float var = Q * (1.f / 128.f) - mean * mean;
    if (t < 128) bnd[bc * DMm + t] = (t1 - mean) / sqrtf(var + 1e-5f) * g[t] + bb[t];
}

// ---------------- K3: QKV + qp/kp (blocks split by which in {q,k,v}) ----------------
__global__ __launch_bounds__(128) void k_qkv(const float* __restrict__ bnd,
                                             const float* __restrict__ qw, const float* __restrict__ qb,
                                             const float* __restrict__ kw, const float* __restrict__ kb,
                                             const float* __restrict__ vw, const float* __restrict__ vb,
                                             const float* __restrict__ w1,
                                             float* __restrict__ q, float* __restrict__ k,
                                             float* __restrict__ v, float* __restrict__ qp,
                                             float* __restrict__ kp) {
    __shared__ float brow[DMm], prow[DMm];
    const int bid = blockIdx.x;
    const int which = bid >> 9;      // 0:q 1:k 2:v
    const int bc = bid & 511;
    const int b = bc >> 8, c = bc & 255;
    const int t = threadIdx.x;
    brow[t] = bnd[bc * DMm + t];
    __syncthreads();
    const float* w  = (which == 0) ? qw : (which == 1) ? kw : vw;
    const float* bi = (which == 0) ? qb : (which == 1) ? kb : vb;
    float val = bi[t] + dot128_4(brow, w + t * DMm);
    const int h = t >> 5, d = t & 31;
    const int gi = ((b * Hh + h) * Cc + c) * DHh + d;
    float* outp = (which == 0) ? q : (which == 1) ? k : v;
    outp[gi] = val;
    if (which < 2) {
        prow[t] = val;
        __syncthreads();
        const float* wr = w1 + d * 96 + ((which == 1) ? 32 : 0);
        float acc = 0.f;
#pragma unroll
        for (int e = 0; e < DHh; ++e) acc = fmaf(prow[h * 32 + e], wr[e], acc);
        ((which == 0) ? qp : kp)[gi] = acc;
    }
}

// ---------------- K4: 256-thread attention, 1 score/thread, redundant wave sort -------------
__global__ __launch_bounds__(256) void k_attn(const float* __restrict__ q,
                                              const float* __restrict__ k,
                                              const float* __restrict__ v,
                                              const float* __restrict__ qp,
                                              const float* __restrict__ kp,
                                              const float* __restrict__ w1,
                                              const float* __restrict__ rb1,
                                              const float* __restrict__ w2,
                                              const float* __restrict__ rb2,
                                              float* __restrict__ aout) {
    __shared__ float w3s[DHh * DHh];
    __shared__ float qs[DHh], qps[DHh], rb1s[DHh], w2s[DHh];
    __shared__ float scL[Cc], aw[Cc], pr[Cc];
    const int bid = blockIdx.x;          // bh*256 + i
    const int t = threadIdx.x;           // 0..255
    const int lane = t & 63;
    const int i = bid & 255, bh = bid >> 8;
    const int rowbase = (bh * Cc + i) * DHh;

    // stage w3 (1024 floats): one float4 per thread
    {
        int row = t >> 3, c4 = t & 7;
        float4 vv = *reinterpret_cast<const float4*>(w1 + row * 96 + 64 + c4 * 4);
        *reinterpret_cast<float4*>(&w3s[row * 32 + c4 * 4]) = vv;
    }
    if (t < 32) {
        qs[t]   = q[rowbase + t];
        qps[t]  = qp[rowbase + t];
        rb1s[t] = rb1[t];
        w2s[t]  = w2[t];
    }
    __syncthreads();
    const float rb2v = rb2[0];

    // --- score for column j = t ---
    float score;
    {
        const int jb = (bh * Cc + t) * DHh;
        float kr[32], kpr[32];
        const float4* k4  = reinterpret_cast<const float4*>(k + jb);
        const float4* kp4 = reinterpret_cast<const float4*>(kp + jb);
#pragma unroll
        for (int m = 0; m < 8; ++m) {
            float4 a = k4[m];  kr[4*m] = a.x; kr[4*m+1] = a.y; kr[4*m+2] = a.z; kr[4*m+3] = a.w;
            float4 bq = kp4[m]; kpr[4*m] = bq.x; kpr[4*m+1] = bq.y; kpr[4*m+2] = bq.z; kpr[4*m+3] = bq.w;
        }
        float p[32];
#pragma unroll
        for (int e = 0; e < 32; ++e) p[e] = qs[e] * kr[e];
        float acc = 0.f;
#pragma unroll 4
        for (int d = 0; d < 32; ++d) {
            const float* wr = &w3s[d * 32];
            float r0 = qps[d] + rb1s[d] + kpr[d], r1 = 0.f, r2 = 0.f, r3 = 0.f;
#pragma unroll
            for (int e = 0; e < 8; ++e) {
                r0 = fmaf(p[e],      wr[e],      r0);
                r1 = fmaf(p[8 + e],  wr[8 + e],  r1);
                r2 = fmaf(p[16 + e], wr[16 + e], r2);
                r3 = fmaf(p[24 + e], wr[24 + e], r3);
            }
            float rr = (r0 + r1) + (r2 + r3);
            acc = fmaf(gelu_exact(rr), w2s[d], acc);
        }
        score = (acc + rb2v) * 0.17677669529663689f; // 1/sqrt(32)
    }
    scL[t] = score;
    __syncthreads();

    // --- each wave redundantly sorts all 256 scores in-register (no barriers) ---
    float v0 = scL[lane], v1 = scL[64 + lane], v2 = scL[128 + lane], v3 = scL[192 + lane];
    auto cx_lane = [&](int k_, int j_) {
        float o0 = __shfl_xor(v0, j_), o1 = __shfl_xor(v1, j_);
        float o2 = __shfl_xor(v2, j_), o3 = __shfl_xor(v3, j_);
        bool lower = ((lane & j_) == 0);
        bool d0 = (((0 * 64 + lane) & k_) == 0);
        bool d1 = (((1 * 64 + lane) & k_) == 0);
        bool d2 = (((2 * 64 + lane) & k_) == 0);
        bool d3 = (((3 * 64 + lane) & k_) == 0);
        v0 = (lower == d0) ? fmaxf(v0, o0) : fminf(v0, o0);
        v1 = (lower == d1) ? fmaxf(v1, o1) : fminf(v1, o1);
        v2 = (lower == d2) ? fmaxf(v2, o2) : fminf(v2, o2);
        v3 = (lower == d3) ? fmaxf(v3, o3) : fminf(v3, o3);
    };
    auto cx_reg1 = [&](int k_) { // j=64: pairs (0,1),(2,3)
        bool dA = (((0 * 64) & k_) == 0);
        bool dB = (((2 * 64) & k_) == 0);
        float aA = v0, bA = v1;
        v0 = dA ? fmaxf(aA, bA) : fminf(aA, bA);
        v1 = dA ? fminf(aA, bA) : fmaxf(aA, bA);
        float aB = v2, bB = v3;
        v2 = dB ? fmaxf(aB, bB) : fminf(aB, bB);
        v3 = dB ? fminf(aB, bB) : fmaxf(aB, bB);
    };
    auto cx_reg2 = [&](int k_) { // j=128: pairs (0,2),(1,3)
        bool dA = (((0 * 64) & k_) == 0);
        bool dB = (((1 * 64) & k_) == 0);
        float aA = v0, bA = v2;
        v0 = dA ? fmaxf(aA, bA) : fminf(aA, bA);
        v2 = dA ? fminf(aA, bA) : fmaxf(aA, bA);
        float aB = v1, bB = v3;
        v1 = dB ? fmaxf(aB, bB) : fminf(aB, bB);
        v3 = dB ? fminf(aB, bB) : fmaxf(aB, bB);
    };
    cx_lane(2, 1);
    cx_lane(4, 2); cx_lane(4, 1);
    cx_lane(8, 4); cx_lane(8, 2); cx_lane(8, 1);
    cx_lane(16, 8); cx_lane(16, 4); cx_lane(16, 2); cx_lane(16, 1);
    cx_lane(32, 16); cx_lane(32, 8); cx_lane(32, 4); cx_lane(32, 2); cx_lane(32, 1);
    cx_lane(64, 32); cx_lane(64, 16); cx_lane(64, 8); cx_lane(64, 4); cx_lane(64, 2); cx_lane(64, 1);
    cx_reg1(128);
    cx_lane(128, 32); cx_lane(128, 16); cx_lane(128, 8); cx_lane(128, 4); cx_lane(128, 2); cx_lane(128, 1);
    cx_reg2(256); cx_reg1(256);
    cx_lane(256, 32); cx_lane(256, 16); cx_lane(256, 8); cx_lane(256, 4); cx_lane(256, 2); cx_lane(256, 1);

    const float minv = __shfl(v0, 63);
    const float mx   = __shfl(v0, 0);

    // --- softmax denominator from sorted regs (tie-exact via >= minv predicate) ---
    float ls = 0.f;
    ls += expf(v0 - mx);                          // top-64: all >= minv by construction
    ls += (v1 >= minv) ? expf(v1 - mx) : 0.f;
    ls += (v2 >= minv) ? expf(v2 - mx) : 0.f;
    ls += (v3 >= minv) ? expf(v3 - mx) : 0.f;
#pragma unroll
    for (int off = 1; off < 64; off <<= 1) ls += __shfl_xor(ls, off);
    const float inv = 1.f / ls;

    aw[t] = (score >= minv) ? expf(score - mx) * inv : 0.f;
    __syncthreads();

    // --- attn @ v: thread = (grp = t>>5 of 8, d = t&31), 32 j's each ---
    const int d = t & 31, grp = t >> 5;
    const float* vbp = v + (bh * Cc + grp * 32) * DHh + d;
    const float* awg = aw + grp * 32;
    float a0 = 0.f, a1 = 0.f, a2v = 0.f, a3v = 0.f;
#pragma unroll
    for (int jj = 0; jj < 32; jj += 4) {
        a0  = fmaf(awg[jj],     vbp[jj * 32],       a0);
        a1  = fmaf(awg[jj + 1], vbp[(jj + 1) * 32], a1);
        a2v = fmaf(awg[jj + 2], vbp[(jj + 2) * 32], a2v);
        a3v = fmaf(awg[jj + 3], vbp[(jj + 3) * 32], a3v);
    }
    pr[t] = (a0 + a1) + (a2v + a3v);
    __syncthreads();
    if (t < 32) {
        float o = pr[t];
#pragma unroll
        for (int g2 = 1; g2 < 8; ++g2) o += pr[g2 * 32 + t];
        const int b = bh >> 2, h = bh & 3;
        aout[(b * Cc + i) * DMm + h * DHh + t] = o;
    }
}

// ---------------- K5: o-proj + LN + FFN + LN (512 thr, 2-barrier LNs) ----------------
__global__ __launch_bounds__(512) void k_ffn(const float* __restrict__ aout,
                                             const float* __restrict__ ow, const float* __restrict__ ob,
                                             const float* __restrict__ n1g, const float* __restrict__ n1b,
                                             const float* __restrict__ fw1, const float* __restrict__ fb1,
                                             const float* __restrict__ fw2, const float* __restrict__ fb2,
                                             const float* __restrict__ n2g, const float* __restrict__ n2b,
                                             float* __restrict__ bnd) {
    __shared__ float arow[DMm], b1row[DMm], ff1[512], ps[4][128];
    __shared__ float redA[8], redB[8], redC[8], redD[8];
    const int bc = blockIdx.x, t = threadIdx.x;
    if (t < 128) arow[t] = aout[bc * DMm + t];
    __syncthreads();
    const int o = t & 127, seg = t >> 7;
    {   // oproj: 4-way split over 32-chunks
        const float* wr = ow + o * DMm + seg * 32;
        const float* ar = arow + seg * 32;
        float pa = 0.f;
#pragma unroll
        for (int e = 0; e < 32; ++e) pa = fmaf(ar[e], wr[e], pa);
        ps[seg][o] = pa;
    }
    __syncthreads();
    float t1 = 0.f;
    if (t < 128) t1 = bnd[bc * DMm + t] + ob[t] + ((ps[0][t] + ps[1][t]) + (ps[2][t] + ps[3][t]));
    float sa = (t < 128) ? t1 : 0.f, sb = (t < 128) ? t1 * t1 : 0.f;
#pragma unroll
    for (int off = 1; off < 64; off <<= 1) { sa += __shfl_xor(sa, off); sb += __shfl_xor(sb, off); }
    if ((t & 63) == 0) { redA[t >> 6] = sa; redB[t >> 6] = sb; }
    __syncthreads();
    float S = 0.f, Q = 0.f;
#pragma unroll
    for (int r = 0; r < 8; ++r) { S += redA[r]; Q += redB[r]; }
    float mean = S * (1.f / 128.f);
    float var = Q * (1.f / 128.f) - mean * mean;
    float b1v = 0.f;
    if (t < 128) {
        b1v = (t1 - mean) / sqrtf(var + 1e-5f) * n1g[t] + n1b[t];
        b1row[t] = b1v;
    }
    __syncthreads();
    // ffn1: one 128-dot per thread (512 outputs)
    ff1[t] = gelu_exact(fb1[t] + dot128_4(b1row, fw1 + t * DMm));
    __syncthreads();
    {   // ffn2: 4-way split over 128-chunks
        ps[seg][o] = dot128_4(ff1 + seg * 128, fw2 + o * 512 + seg * 128);
    }
    __syncthreads();
    float t2 = 0.f;
    if (t < 128) t2 = b1v + fb2[t] + ((ps[0][t] + ps[1][t]) + (ps[2][t] + ps[3][t]));
    sa = (t < 128) ? t2 : 0.f; sb = (t < 128) ? t2 * t2 : 0.f;
#pragma unroll
    for (int off = 1; off < 64; off <<= 1) { sa += __shfl_xor(sa, off); sb += __shfl_xor(sb, off); }
    if ((t & 63) == 0) { redC[t >> 6] = sa; redD[t >> 6] = sb; }
    __syncthreads();
    S = 0.f; Q = 0.f;
#pragma unroll
    for (int r = 0; r < 8; ++r) { S += redC[r]; Q += redD[r]; }
    mean = S * (1.f / 128.f);
    var = Q * (1.f / 128.f) - mean * mean;
    if (t < 128) bnd[bc * DMm + t] = (t2 - mean) / sqrtf(var + 1e-5f) * n2g[t] + n2b[t];
}

// ---------------- K6+K7 fused: slots GRU (s<64) and task-query readout (s==64) -------------
__global__ __launch_bounds__(256) void k_slots(const float* __restrict__ bnd,
                                               const float* __restrict__ slots,
                                               const float* __restrict__ tq,
                                               const float* __restrict__ wih,
                                               const float* __restrict__ whh,
                                               const float* __restrict__ bih,
                                               const float* __restrict__ bhh,
                                               float* __restrict__ contrib,
                                               float* __restrict__ hbuf) {
    __shared__ float sl[DMm], a2[Cc], ctx2[2][128], ctxs[DMm], giS[3 * DMm], ghS[3 * DMm];
    __shared__ float redM[4], redS[4];
    const int bid = blockIdx.x;
    const int b = bid / 65, s = bid % 65;
    const int t = threadIdx.x;
    if (t < DMm) sl[t] = (s < Ss) ? slots[s * DMm + t] : tq[t];
    __syncthreads();
    float sv = dot128_4(sl, bnd + (b * Cc + t) * DMm) * 0.08838834764831845f;
    float m = sv;
#pragma unroll
    for (int off = 1; off < 64; off <<= 1) m = fmaxf(m, __shfl_xor(m, off));
    if ((t & 63) == 0) redM[t >> 6] = m;
    __syncthreads();
    float mxv = fmaxf(fmaxf(redM[0], redM[1]), fmaxf(redM[2], redM[3]));
    float ev = expf(sv - mxv);
    float su = ev;
#pragma unroll
    for (int off = 1; off < 64; off <<= 1) su += __shfl_xor(su, off);
    if ((t & 63) == 0) redS[t >> 6] = su;
    __syncthreads();
    float sum = (redS[0] + redS[1]) + (redS[2] + redS[3]);
    a2[t] = ev / sum;
    __syncthreads();
    {   // ctx: 2-way split over c
        const int o = t & 127, seg = t >> 7;
        float cacc = 0.f;
        for (int cc = 0; cc < 128; ++cc) {
            int c = seg * 128 + cc;
            cacc = fmaf(a2[c], bnd[(b * Cc + c) * DMm + o], cacc);
        }
        ctx2[seg][o] = cacc;
    }
    __syncthreads();
    if (t < DMm) ctxs[t] = ctx2[0][t] + ctx2[1][t];
    __syncthreads();
    if (s == Ss) {
        if (t < DMm) hbuf[b * DMm + t] = ctxs[t];
        return;
    }
    giS[t] = bih[t] + dot128_4(ctxs, wih + t * DMm);
    ghS[t] = bhh[t] + dot128_4(sl, whh + t * DMm);
    if (t < DMm) {
        int o = 256 + t;
        giS[o] = bih[o] + dot128_4(ctxs, wih + o * DMm);
        ghS[o] = bhh[o] + dot128_4(sl, whh + o * DMm);
    }
    __syncthreads();
    if (t < DMm) {
        float r = 1.f / (1.f + expf(-(giS[t] + ghS[t])));
        float z = 1.f / (1.f + expf(-(giS[128 + t] + ghS[128 + t])));
        float n = tanhf(giS[256 + t] + r * ghS[256 + t]);
        contrib[(b * Ss + s) * DMm + t] = (1.f - z) * n + z * sl[t];
    }
}

// ---------------- K8: mem LN + head ----------------
__global__ __launch_bounds__(128) void k_final(const float* __restrict__ contrib,
                                               const float* __restrict__ hbuf,
                                               const float* __restrict__ mg, const float* __restrict__ mb,
                                               const float* __restrict__ hw, const float* __restrict__ hb,
                                               float* __restrict__ out) {
    __shared__ float hm[DMm], redA[2], redB[2];
    const int b = blockIdx.x, t = threadIdx.x;
    float acc = 0.f;
    for (int s = 0; s < Ss; ++s) acc += contrib[(b * Ss + s) * DMm + t];
    acc *= (1.f / (float)Ss);
    float sa = acc, sb = acc * acc;
#pragma unroll
    for (int off = 1; off < 64; off <<= 1) { sa += __shfl_xor(sa, off); sb += __shfl_xor(sb, off); }
    if ((t & 63) == 0) { redA[t >> 6] = sa; redB[t >> 6] = sb; }
    __syncthreads();
    float S = redA[0] + redA[1], Q = redB[0] + redB[1];
    float mean = S * (1.f / 128.f);
    float var = Q * (1.f / 128.f) - mean * mean;
    float memv = (acc - mean) / sqrtf(var + 1e-5f) * mg[t] + mb[t];
    hm[t] = hbuf[b * DMm + t] + memv;
    __syncthreads();
    if (t < OUTn) {
        float o = hb[t];
        const float* wr = hw + t * DMm;
#pragma unroll 16
        for (int e = 0; e < DMm; ++e) o = fmaf(hm[e], wr[e], o);
        out[b * OUTn + t] = o;
    }
}

extern "C" void kernel_launch(void* const* d_in, const int* in_sizes, int n_in,
                              void* d_out, int out_size, void* d_ws, size_t ws_size,
                              hipStream_t stream) {
    const float* x         = (const float*)d_in[0];
    const float* emb_roles = (const float*)d_in[1];
    const float* filler_w  = (const float*)d_in[2];
    const float* conv_w    = (const float*)d_in[3];
    const float* conv_b    = (const float*)d_in[4];
    const float* outer_w   = (const float*)d_in[5];
    const float* enc_ng    = (const float*)d_in[6];
    const float* enc_nb    = (const float*)d_in[7];
    const float* qw        = (const float*)d_in[8];
    const float* qb        = (const float*)d_in[9];
    const float* kw        = (const float*)d_in[10];
    const float* kb        = (const float*)d_in[11];
    const float* vw        = (const float*)d_in[12];
    const float* vb        = (const float*)d_in[13];
    const float* rel_w1    = (const float*)d_in[14];
    const float* rel_b1    = (const float*)d_in[15];
    const float* rel_w2    = (const float*)d_in[16];
    const float* rel_b2    = (const float*)d_in[17];
    const float* ow        = (const float*)d_in[18];
    const float* ob        = (const float*)d_in[19];
    const float* n1g       = (const float*)d_in[20];
    const float* n1b       = (const float*)d_in[21];
    const float* n2g       = (const float*)d_in[22];
    const float* n2b       = (const float*)d_in[23];
    const float* ffn_w1    = (const float*)d_in[24];
    const float* ffn_b1    = (const float*)d_in[25];
    const float* ffn_w2    = (const float*)d_in[26];
    const float* ffn_b2    = (const float*)d_in[27];
    const float* task_q    = (const float*)d_in[28];
    const float* slots     = (const float*)d_in[29];
    const float* gru_wih   = (const float*)d_in[30];
    const float* gru_whh   = (const float*)d_in[31];
    const float* gru_bih   = (const float*)d_in[32];
    const float* gru_bhh   = (const float*)d_in[33];
    const float* mem_ng    = (const float*)d_in[34];
    const float* mem_nb    = (const float*)d_in[35];
    const float* head_w    = (const float*)d_in[36];
    const float* head_b    = (const float*)d_in[37];

    float* ws = (float*)d_ws;
    const int BC = Bb * Cc;                 // 512
    const int BHCD = Bb * Hh * Cc * DHh;    // 65536
    float* valsb = ws;                      // 512
    float* mzb   = valsb + BC;              // 512
    float* bnd   = mzb + BC;                // 65536
    float* qB    = bnd + BC * DMm;
    float* kB    = qB + BHCD;
    float* vB    = kB + BHCD;
    float* qpB   = vB + BHCD;
    float* kpB   = qpB + BHCD;
    float* aout  = kpB + BHCD;              // 65536
    float* hbuf  = aout + BC * DMm;         // 256
    float* contrib = hbuf + Bb * DMm;       // 16384

    k_topk<<<Bb, 1024, 0, stream>>>(x, valsb, mzb);
    k_encode<<<BC, 256, 0, stream>>>(valsb, mzb, emb_roles, filler_w, conv_w, conv_b,
                                     outer_w, enc_ng, enc_nb, bnd);
    for (int l = 0; l < Ll; ++l) {
        k_qkv<<<3 * BC, 128, 0, stream>>>(bnd,
                                          qw + l * DMm * DMm, qb + l * DMm,
                                          kw + l * DMm * DMm, kb + l * DMm,
                                          vw + l * DMm * DMm, vb + l * DMm,
                                          rel_w1 + l * DHh * 3 * DHh,
                                          qB, kB, vB, qpB, kpB);
        k_attn<<<Bb * Hh * Cc, 256, 0, stream>>>(qB, kB, vB, qpB, kpB,
                                                 rel_w1 + l * DHh * 3 * DHh,
                                                 rel_b1 + l * DHh,
                                                 rel_w2 + l * DHh,
                                                 rel_b2 + l,
                                                 aout);
        k_ffn<<<BC, 512, 0, stream>>>(aout,
                                      ow + l * DMm * DMm, ob + l * DMm,
                                      n1g + l * DMm, n1b + l * DMm,
                                      ffn_w1 + l * 4 * DMm * DMm, ffn_b1 + l * 4 * DMm,
                                      ffn_w2 + l * 4 * DMm * DMm, ffn_b2 + l * DMm,
                                      n2g + l * DMm, n2b + l * DMm,
                                      bnd);
    }
    k_slots<<<Bb * (Ss + 1), 256, 0, stream>>>(bnd, slots, task_q, gru_wih, gru_whh,
                                               gru_bih, gru_bhh, contrib, hbuf);
    k_final<<<Bb, 128, 0, stream>>>(contrib, hbuf, mem_ng, mem_nb, head_w, head_b, (float*)d_out);
}